// Round 11
// baseline (231.037 us; speedup 1.0000x reference)
//
#include <hip/hip_runtime.h>
#include <hip/hip_bf16.h>
#include <math.h>

#define HH 64            // hidden channels
#define EPS 1e-5f
#define STAGE_CAP 12288  // per-bucket LDS staging capacity (3x avg bucket size)
#define NBLK_SCAT 192    // partition blocks (must match between hist and scatter)
#define PER_LANE 3       // ceil(NBLK_SCAT / 64)

// ---------------------------------------------------------------- utilities
__device__ __forceinline__ int lower_bound_i(const int* a, int n, int key) {
    int lo = 0, hi = n;
    while (lo < hi) { int mid = (lo + hi) >> 1; if (a[mid] < key) lo = mid + 1; else hi = mid; }
    return lo;
}

__device__ __forceinline__ unsigned short f2bf(float f) {
    unsigned int u = __float_as_uint(f);
    unsigned int r = (u + 0x7FFFu + ((u >> 16) & 1u)) >> 16;   // RNE
    return (unsigned short)r;
}
__device__ __forceinline__ float bf2f(unsigned short b) {
    return __uint_as_float(((unsigned int)b) << 16);
}
__device__ __forceinline__ float bflo(unsigned int u) { return __uint_as_float(u << 16); }
__device__ __forceinline__ float bfhi(unsigned int u) { return __uint_as_float(u & 0xFFFF0000u); }

// ---------------------------------------------------------------- init (gsum only)
__global__ void init_kernel(float* gsum, int NG) {
    int t = blockIdx.x * blockDim.x + threadIdx.x;
    if (t < NG) gsum[t] = 0.f;
}

// pass A1: per-block histogram over buckets (LDS only, no global atomics)
__global__ __launch_bounds__(256) void hist_kernel(const int* __restrict__ dst,
        int* __restrict__ blockhist, int E, int chunk) {
    __shared__ int hist[256];
    int tid = threadIdx.x, blk = blockIdx.x;
    hist[tid] = 0;
    __syncthreads();
    int s = blk * chunk, e = s + chunk; if (e > E) e = E;
    for (int i = s + tid; i < e; i += 256) atomicAdd(&hist[dst[i] >> 8], 1);
    __syncthreads();
    blockhist[blk * 256 + tid] = hist[tid];
}

// pass A1b: single block; column-sum blockhist -> bucket totals -> exclusive scan
__global__ __launch_bounds__(256) void bucketscan_kernel(const int* __restrict__ blockhist,
        int* __restrict__ bucketbase, int NB, int E) {
    __shared__ int wsum2[4];
    int tid = threadIdx.x, lane = tid & 63, wid = tid >> 6;
    int s = 0;
    if (tid < NB) {
        for (int i = 0; i < NBLK_SCAT; ++i) s += blockhist[i * 256 + tid];
    }
    int incl = s;
    #pragma unroll
    for (int off = 1; off < 64; off <<= 1) {
        int n = __shfl_up(incl, off);
        if (lane >= off) incl += n;
    }
    if (lane == 63) wsum2[wid] = incl;
    __syncthreads();
    int wbase = 0;
    #pragma unroll
    for (int k = 0; k < 4; ++k) if (k < wid) wbase += wsum2[k];
    if (tid < NB) bucketbase[tid] = wbase + incl - s;
    if (tid == 0) bucketbase[NB] = E;
}

// pass A2: per-bucket column scan of blockhist -> per-block write cursors
__global__ __launch_bounds__(64) void offsets_kernel(const int* __restrict__ bucketbase,
        int* __restrict__ blockhist, int NB) {
    int b = blockIdx.x;
    int lane = threadIdx.x;
    int v[PER_LANE];
    int base = lane * PER_LANE;
    int s = 0;
    #pragma unroll
    for (int k = 0; k < PER_LANE; ++k) {
        int i = base + k;
        v[k] = (i < NBLK_SCAT) ? blockhist[i * 256 + b] : 0;
        s += v[k];
    }
    int incl = s;
    #pragma unroll
    for (int off = 1; off < 64; off <<= 1) {
        int n = __shfl_up(incl, off);
        if (lane >= off) incl += n;
    }
    int excl = incl - s + bucketbase[b];
    #pragma unroll
    for (int k = 0; k < PER_LANE; ++k) {
        int i = base + k;
        if (i < NBLK_SCAT) { blockhist[i * 256 + b] = excl; excl += v[k]; }
    }
}

// pass A3: scatter edges to bucket regions using LDS cursors
__global__ __launch_bounds__(256) void scatterA_kernel(const int* __restrict__ src,
        const int* __restrict__ dst, const int* __restrict__ blockhist,
        int* __restrict__ buf, int E, int chunk) {
    __shared__ int lcur[256];
    int tid = threadIdx.x, blk = blockIdx.x;
    lcur[tid] = blockhist[blk * 256 + tid];
    __syncthreads();
    int s = blk * chunk, e = s + chunk; if (e > E) e = E;
    for (int i = s + tid; i < e; i += 256) {
        int d = dst[i];
        int b = d >> 8;
        int p = atomicAdd(&lcur[b], 1);
        buf[p] = ((d & 255) << 24) | src[i];    // pack local-dst | src (src < 2^24)
    }
}

// pass B: per bucket: local degree hist + scan (writes rowstart, dis), permute to csr
__global__ __launch_bounds__(256) void bucket_to_csr_kernel(const int* __restrict__ buf,
        const int* __restrict__ bucketbase, int* __restrict__ rowstart,
        float* __restrict__ dis, int* __restrict__ csr, int N, int E) {
    __shared__ int ldeg[256];
    __shared__ int cur[256];
    __shared__ int wsum2[4];
    __shared__ int stage[STAGE_CAP];
    int b = blockIdx.x;
    int nodeStart = b << 8;
    int nodeEnd = nodeStart + 256; if (nodeEnd > N) nodeEnd = N;
    int nloc = nodeEnd - nodeStart;
    int base = bucketbase[b];
    int nE = bucketbase[b + 1] - base;
    int tid = threadIdx.x;
    int lane = tid & 63, wid = tid >> 6;
    ldeg[tid] = 0;
    __syncthreads();
    for (int i = tid; i < nE; i += 256)
        atomicAdd(&ldeg[((unsigned)buf[base + i]) >> 24], 1);
    __syncthreads();
    int d = ldeg[tid];
    int incl = d;
    #pragma unroll
    for (int off = 1; off < 64; off <<= 1) {
        int n = __shfl_up(incl, off);
        if (lane >= off) incl += n;
    }
    if (lane == 63) wsum2[wid] = incl;
    __syncthreads();
    int wbase = 0;
    #pragma unroll
    for (int k = 0; k < 4; ++k) if (k < wid) wbase += wsum2[k];
    int excl = wbase + incl - d;
    cur[tid] = excl;
    if (tid < nloc) {
        rowstart[nodeStart + tid] = base + excl;
        dis[nodeStart + tid] = rsqrtf((float)d + 1.0f);
    }
    if (b == 0 && tid == 0) rowstart[N] = E;
    __syncthreads();
    if (nE <= STAGE_CAP) {
        for (int i = tid; i < nE; i += 256) {
            int u = buf[base + i];
            int l = ((unsigned)u) >> 24;
            int p = atomicAdd(&cur[l], 1);
            stage[p] = u & 0xFFFFFF;
        }
        __syncthreads();
        for (int i = tid; i < nE; i += 256) csr[base + i] = stage[i];
    } else {
        for (int i = tid; i < nE; i += 256) {
            int u = buf[base + i];
            int l = ((unsigned)u) >> 24;
            int p = atomicAdd(&cur[l], 1);
            csr[base + p] = u & 0xFFFFFF;
        }
    }
}

// ---------------------------------------------------------------- layer 1 GEMM (IN=3) -> bf16 mt
__global__ void mt1_kernel(const float* __restrict__ x, const float* __restrict__ W1,
                           const float* __restrict__ dis, unsigned short* __restrict__ mt, int N) {
    int t = blockIdx.x * blockDim.x + threadIdx.x;
    if (t < N * HH) {
        int v = t >> 6, c = t & 63;
        float m = x[v * 3 + 0] * W1[0 * HH + c]
                + x[v * 3 + 1] * W1[1 * HH + c]
                + x[v * 3 + 2] * W1[2 * HH + c];
        mt[t] = f2bf(m * dis[v]);
    }
}

// ---------------------------------------------------------------- gather core (wave, one node)
__device__ __forceinline__ float gather_row(const unsigned short* __restrict__ mt,
        const int* __restrict__ csr_src, int start, int end, int lane) {
    float acc = 0.f;
    for (int base = start; base < end; base += 64) {
        int idx = (base + lane < end) ? csr_src[base + lane] : 0;
        int cnt = end - base; if (cnt > 64) cnt = 64;
        int j = 0;
        for (; j + 15 < cnt; j += 16) {
            int s0 = __shfl(idx, j),      s1 = __shfl(idx, j + 1);
            int s2 = __shfl(idx, j + 2),  s3 = __shfl(idx, j + 3);
            int s4 = __shfl(idx, j + 4),  s5 = __shfl(idx, j + 5);
            int s6 = __shfl(idx, j + 6),  s7 = __shfl(idx, j + 7);
            int s8 = __shfl(idx, j + 8),  s9 = __shfl(idx, j + 9);
            int sa = __shfl(idx, j + 10), sb = __shfl(idx, j + 11);
            int sc = __shfl(idx, j + 12), sd = __shfl(idx, j + 13);
            int se = __shfl(idx, j + 14), sf = __shfl(idx, j + 15);
            float v0 = bf2f(mt[s0 * HH + lane]);
            float v1 = bf2f(mt[s1 * HH + lane]);
            float v2 = bf2f(mt[s2 * HH + lane]);
            float v3 = bf2f(mt[s3 * HH + lane]);
            float v4 = bf2f(mt[s4 * HH + lane]);
            float v5 = bf2f(mt[s5 * HH + lane]);
            float v6 = bf2f(mt[s6 * HH + lane]);
            float v7 = bf2f(mt[s7 * HH + lane]);
            float v8 = bf2f(mt[s8 * HH + lane]);
            float v9 = bf2f(mt[s9 * HH + lane]);
            float va = bf2f(mt[sa * HH + lane]);
            float vb = bf2f(mt[sb * HH + lane]);
            float vc = bf2f(mt[sc * HH + lane]);
            float vd = bf2f(mt[sd * HH + lane]);
            float ve = bf2f(mt[se * HH + lane]);
            float vf = bf2f(mt[sf * HH + lane]);
            acc += v0; acc += v1; acc += v2; acc += v3;
            acc += v4; acc += v5; acc += v6; acc += v7;
            acc += v8; acc += v9; acc += va; acc += vb;
            acc += vc; acc += vd; acc += ve; acc += vf;
        }
        for (; j + 7 < cnt; j += 8) {
            int s0 = __shfl(idx, j),     s1 = __shfl(idx, j + 1);
            int s2 = __shfl(idx, j + 2), s3 = __shfl(idx, j + 3);
            int s4 = __shfl(idx, j + 4), s5 = __shfl(idx, j + 5);
            int s6 = __shfl(idx, j + 6), s7 = __shfl(idx, j + 7);
            float v0 = bf2f(mt[s0 * HH + lane]);
            float v1 = bf2f(mt[s1 * HH + lane]);
            float v2 = bf2f(mt[s2 * HH + lane]);
            float v3 = bf2f(mt[s3 * HH + lane]);
            float v4 = bf2f(mt[s4 * HH + lane]);
            float v5 = bf2f(mt[s5 * HH + lane]);
            float v6 = bf2f(mt[s6 * HH + lane]);
            float v7 = bf2f(mt[s7 * HH + lane]);
            acc += v0; acc += v1; acc += v2; acc += v3;
            acc += v4; acc += v5; acc += v6; acc += v7;
        }
        for (; j < cnt; ++j) acc += bf2f(mt[__shfl(idx, j) * HH + lane]);
    }
    return acc;
}

// ---------------------------------------------------------------- fused gather+BN+ReLU+GEMM(Wnext)
// One 64-node tile per block, 4 waves x 16 nodes. h row kept in LDS (fp32),
// consumed immediately by the same wave for the next-layer GEMM. No h global traffic.
__global__ __launch_bounds__(256) void gather_gemm_kernel(const unsigned short* __restrict__ mt_in,
        const int* __restrict__ rowstart, const int* __restrict__ csr_src,
        const float* __restrict__ dis, const float* __restrict__ bias,
        const float* __restrict__ gam, const float* __restrict__ beta,
        const float* __restrict__ mu, const float* __restrict__ var,
        const float* __restrict__ Wnext, unsigned short* __restrict__ mt_out, int N) {
    __shared__ unsigned int wsp[HH * 34];   // W^T packed bf16x2: [c][k2]
    __shared__ float hsf[64][68];           // h tile fp32, pad 68
    int tid = threadIdx.x;
    int lane = tid & 63, wid = tid >> 6;
    {
        int c = tid & 63;
        for (int k2 = tid >> 6; k2 < 32; k2 += 4) {
            float a = Wnext[(2 * k2) * HH + c];
            float b = Wnext[(2 * k2 + 1) * HH + c];
            wsp[c * 34 + k2] = (unsigned)f2bf(a) | ((unsigned)f2bf(b) << 16);
        }
    }
    __syncthreads();
    int v0 = blockIdx.x * 64;
    float ginv = rsqrtf(var[lane] + EPS) * gam[lane];
    float gmu = mu[lane], gbe = beta[lane], gbi = bias[lane];
    for (int n = wid * 16; n < wid * 16 + 16; ++n) {
        int v = v0 + n;
        if (v >= N) break;
        int start = rowstart[v], end = rowstart[v + 1];
        float dv = dis[v];
        float acc = bf2f(mt_in[(size_t)v * HH + lane]);   // self-loop term
        acc += gather_row(mt_in, csr_src, start, end, lane);
        float val = acc * dv + gbi;
        val = (val - gmu) * ginv + gbe;
        val = fmaxf(val, 0.f);
        hsf[n][lane] = val;
        // GEMM row: m[c] = sum_k h[k] * Wnext[k][c]; then * dis[v]
        float acc2 = 0.f;
        #pragma unroll 4
        for (int k4 = 0; k4 < 16; ++k4) {
            float4 hv = *(const float4*)&hsf[n][4 * k4];
            uint2 wv = *(const uint2*)&wsp[lane * 34 + 2 * k4];
            acc2 = fmaf(hv.x, bflo(wv.x), acc2);
            acc2 = fmaf(hv.y, bfhi(wv.x), acc2);
            acc2 = fmaf(hv.z, bflo(wv.y), acc2);
            acc2 = fmaf(hv.w, bfhi(wv.y), acc2);
        }
        mt_out[(size_t)v * HH + lane] = f2bf(acc2 * dv);
    }
}

// ---------------------------------------------------------------- fused gather+BN+ReLU+pool
// Layer-3 gather; run-accumulates into gsum by (sorted) batch id. No h3 buffer.
__global__ __launch_bounds__(256) void gather_pool_kernel(const unsigned short* __restrict__ mt_in,
        const int* __restrict__ rowstart, const int* __restrict__ csr_src,
        const float* __restrict__ dis, const float* __restrict__ bias,
        const float* __restrict__ gam, const float* __restrict__ beta,
        const float* __restrict__ mu, const float* __restrict__ var,
        const int* __restrict__ batch, float* __restrict__ gsum, int N) {
    int tid = threadIdx.x;
    int lane = tid & 63, wid = tid >> 6;
    int v0 = (blockIdx.x * 4 + wid) * 16;
    if (v0 >= N) return;
    int vend = v0 + 16; if (vend > N) vend = N;
    float ginv = rsqrtf(var[lane] + EPS) * gam[lane];
    float gmu = mu[lane], gbe = beta[lane], gbi = bias[lane];
    int g = batch[v0];
    float accrun = 0.f;
    for (int v = v0; v < vend; ++v) {
        int start = rowstart[v], end = rowstart[v + 1];
        float dv = dis[v];
        float acc = bf2f(mt_in[(size_t)v * HH + lane]);
        acc += gather_row(mt_in, csr_src, start, end, lane);
        float val = acc * dv + gbi;
        val = (val - gmu) * ginv + gbe;
        val = fmaxf(val, 0.f);
        int gv = batch[v];
        if (gv != g) {
            atomicAdd(&gsum[g * HH + lane], accrun);
            g = gv; accrun = 0.f;
        }
        accrun += val;
    }
    atomicAdd(&gsum[g * HH + lane], accrun);
}

// ---------------------------------------------------------------- MLP heads (+ mean divide)
__global__ __launch_bounds__(64) void heads_kernel(const float* __restrict__ gsum,
        const int* __restrict__ batch, int N,
        const float* __restrict__ thW1, const float* __restrict__ thb1,
        const float* __restrict__ thW2, const float* __restrict__ thb2,
        const float* __restrict__ lhW1, const float* __restrict__ lhb1,
        const float* __restrict__ lhW2, const float* __restrict__ lhb2,
        const float* __restrict__ shW1, const float* __restrict__ shb1,
        const float* __restrict__ shW2, const float* __restrict__ shb2,
        float* __restrict__ out, int B) {
    int g = blockIdx.x, t = threadIdx.x;
    __shared__ float ge[HH];
    __shared__ float hT[32], hL[32], hS[16];
    int lo = lower_bound_i(batch, N, g);
    int hi = lower_bound_i(batch, N, g + 1);
    float cnt = (float)(hi - lo);
    ge[t] = gsum[g * HH + t] / fmaxf(cnt, 1.0f);
    __syncthreads();
    if (t < 32) {
        float a = thb1[t];
        for (int k = 0; k < HH; ++k) a += ge[k] * thW1[k * 32 + t];
        hT[t] = fmaxf(a, 0.f);
    } else {
        int j = t - 32;
        float a = lhb1[j];
        for (int k = 0; k < HH; ++k) a += ge[k] * lhW1[k * 32 + j];
        hL[j] = fmaxf(a, 0.f);
    }
    __syncthreads();
    if (t < 16) {
        float a = shb1[t];
        for (int k = 0; k < HH; ++k) a += ge[k] * shW1[k * 16 + t];
        hS[t] = fmaxf(a, 0.f);
    }
    __syncthreads();
    if (t < 6) {
        float a = thb2[t];
        for (int j = 0; j < 32; ++j) a += hT[j] * thW2[j * 6 + t];
        out[g * 6 + t] = a;
    } else if (t >= 8 && t < 10) {
        int o = t - 8;
        float a = lhb2[o];
        for (int j = 0; j < 32; ++j) a += hL[j] * lhW2[j * 2 + o];
        out[B * 6 + g * 2 + o] = 1.f / (1.f + expf(-a));
    } else if (t == 12) {
        float a = shb2[0];
        for (int j = 0; j < 16; ++j) a += hS[j] * shW2[j];
        out[B * 8 + g] = 1.f / (1.f + expf(-a));
    }
}

// ---------------------------------------------------------------- launch
extern "C" void kernel_launch(void* const* d_in, const int* in_sizes, int n_in,
                              void* d_out, int out_size, void* d_ws, size_t ws_size,
                              hipStream_t stream) {
    const float* x   = (const float*)d_in[0];
    const int*   ei  = (const int*)d_in[1];
    const int*   bat = (const int*)d_in[2];
    const float* W1 = (const float*)d_in[3];  const float* b1 = (const float*)d_in[4];
    const float* W2 = (const float*)d_in[5];  const float* b2 = (const float*)d_in[6];
    const float* W3 = (const float*)d_in[7];  const float* b3 = (const float*)d_in[8];
    const float* bn1g = (const float*)d_in[9];  const float* bn1b = (const float*)d_in[10];
    const float* bn1m = (const float*)d_in[11]; const float* bn1v = (const float*)d_in[12];
    const float* bn2g = (const float*)d_in[13]; const float* bn2b = (const float*)d_in[14];
    const float* bn2m = (const float*)d_in[15]; const float* bn2v = (const float*)d_in[16];
    const float* bn3g = (const float*)d_in[17]; const float* bn3b = (const float*)d_in[18];
    const float* bn3m = (const float*)d_in[19]; const float* bn3v = (const float*)d_in[20];
    const float* thW1 = (const float*)d_in[21]; const float* thb1 = (const float*)d_in[22];
    const float* thW2 = (const float*)d_in[23]; const float* thb2 = (const float*)d_in[24];
    const float* lhW1 = (const float*)d_in[25]; const float* lhb1 = (const float*)d_in[26];
    const float* lhW2 = (const float*)d_in[27]; const float* lhb2 = (const float*)d_in[28];
    const float* shW1 = (const float*)d_in[29]; const float* shb1 = (const float*)d_in[30];
    const float* shW2 = (const float*)d_in[31]; const float* shb2 = (const float*)d_in[32];
    float* out = (float*)d_out;

    const int N = in_sizes[0] / 3;
    const int E = in_sizes[1] / 2;
    const int B = out_size / 9;          // 6 + 2 + 1 per graph
    const int NB = (N + 255) >> 8;       // buckets of 256 nodes
    const int* esrc = ei;
    const int* edst = ei + E;

    // workspace layout (256B aligned)
    char* w = (char*)d_ws;
    size_t off = 0;
    auto alloc = [&](size_t bytes) -> void* {
        void* p = w + off;
        off += (bytes + 255) & ~(size_t)255;
        return p;
    };
    int*   rowstart   = (int*)  alloc((size_t)(N + 1) * 4);
    float* dis        = (float*)alloc((size_t)N * 4);
    int*   csr        = (int*)  alloc((size_t)E * 4);
    int*   blockhist  = (int*)  alloc((size_t)NBLK_SCAT * 256 * 4);
    int*   bucketbase = (int*)  alloc((size_t)(NB + 1) * 4);
    unsigned short* mtA = (unsigned short*)alloc((size_t)N * HH * 2);
    unsigned short* mtB = (unsigned short*)alloc((size_t)N * HH * 2);
    float* gsum       = (float*)alloc((size_t)B * HH * 4);
    int*   bucketbuf  = (int*)mtA;       // reuse: free until mt1_kernel (E*4 <= N*HH*2)
    (void)ws_size;

    const int TB = 256;
    const int echunk = (E + NBLK_SCAT - 1) / NBLK_SCAT;
    // CSR build: hist -> bucketscan -> offsets -> scatter -> per-bucket deg/scan/permute
    init_kernel<<<(B * HH + TB - 1) / TB, TB, 0, stream>>>(gsum, B * HH);
    hist_kernel<<<NBLK_SCAT, TB, 0, stream>>>(edst, blockhist, E, echunk);
    bucketscan_kernel<<<1, TB, 0, stream>>>(blockhist, bucketbase, NB, E);
    offsets_kernel<<<NB, 64, 0, stream>>>(bucketbase, blockhist, NB);
    scatterA_kernel<<<NBLK_SCAT, TB, 0, stream>>>(esrc, edst, blockhist, bucketbuf, E, echunk);
    bucket_to_csr_kernel<<<NB, TB, 0, stream>>>(bucketbuf, bucketbase, rowstart, dis, csr, N, E);

    int tileBlocks = (N + 63) / 64;
    // layer 1 message table
    mt1_kernel<<<(N * HH + TB - 1) / TB, TB, 0, stream>>>(x, W1, dis, mtA, N);
    // fused: gather(bn1)+ReLU -> GEMM(W2) -> mtB
    gather_gemm_kernel<<<tileBlocks, TB, 0, stream>>>(mtA, rowstart, csr, dis,
            b1, bn1g, bn1b, bn1m, bn1v, W2, mtB, N);
    // fused: gather(bn2)+ReLU -> GEMM(W3) -> mtA
    gather_gemm_kernel<<<tileBlocks, TB, 0, stream>>>(mtB, rowstart, csr, dis,
            b2, bn2g, bn2b, bn2m, bn2v, W3, mtA, N);
    // fused: gather(bn3)+ReLU -> pool accumulate -> gsum
    gather_pool_kernel<<<tileBlocks, TB, 0, stream>>>(mtA, rowstart, csr, dis,
            b3, bn3g, bn3b, bn3m, bn3v, bat, gsum, N);

    heads_kernel<<<B, 64, 0, stream>>>(gsum, bat, N, thW1, thb1, thW2, thb2,
            lhW1, lhb1, lhW2, lhb2, shW1, shb1, shW2, shb2, out, B);
}

// Round 12
// 218.140 us; speedup vs baseline: 1.0591x; 1.0591x over previous
//
#include <hip/hip_runtime.h>
#include <hip/hip_bf16.h>
#include <math.h>

#define HH 64            // hidden channels
#define EPS 1e-5f
#define STAGE_CAP 12288  // per-bucket LDS staging capacity (3x avg bucket size)
#define NBLK_SCAT 192    // partition blocks (must match between hist and scatter)
#define PER_LANE 3       // ceil(NBLK_SCAT / 64)

// ---------------------------------------------------------------- utilities
__device__ __forceinline__ int lower_bound_i(const int* a, int n, int key) {
    int lo = 0, hi = n;
    while (lo < hi) { int mid = (lo + hi) >> 1; if (a[mid] < key) lo = mid + 1; else hi = mid; }
    return lo;
}

__device__ __forceinline__ unsigned short f2bf(float f) {
    unsigned int u = __float_as_uint(f);
    unsigned int r = (u + 0x7FFFu + ((u >> 16) & 1u)) >> 16;   // RNE
    return (unsigned short)r;
}
__device__ __forceinline__ float bf2f(unsigned short b) {
    return __uint_as_float(((unsigned int)b) << 16);
}
__device__ __forceinline__ float bflo(unsigned int u) { return __uint_as_float(u << 16); }
__device__ __forceinline__ float bfhi(unsigned int u) { return __uint_as_float(u & 0xFFFF0000u); }

// ---------------------------------------------------------------- init (gsum only)
__global__ void init_kernel(float* gsum, int NG) {
    int t = blockIdx.x * blockDim.x + threadIdx.x;
    if (t < NG) gsum[t] = 0.f;
}

// pass A1: per-block histogram over buckets (LDS only, no global atomics)
__global__ __launch_bounds__(256) void hist_kernel(const int* __restrict__ dst,
        int* __restrict__ blockhist, int E, int chunk) {
    __shared__ int hist[256];
    int tid = threadIdx.x, blk = blockIdx.x;
    hist[tid] = 0;
    __syncthreads();
    int s = blk * chunk, e = s + chunk; if (e > E) e = E;
    for (int i = s + tid; i < e; i += 256) atomicAdd(&hist[dst[i] >> 8], 1);
    __syncthreads();
    blockhist[blk * 256 + tid] = hist[tid];
}

// pass A1b: single block; column-sum blockhist -> bucket totals -> exclusive scan
__global__ __launch_bounds__(256) void bucketscan_kernel(const int* __restrict__ blockhist,
        int* __restrict__ bucketbase, int NB, int E) {
    __shared__ int wsum2[4];
    int tid = threadIdx.x, lane = tid & 63, wid = tid >> 6;
    int s = 0;
    if (tid < NB) {
        for (int i = 0; i < NBLK_SCAT; ++i) s += blockhist[i * 256 + tid];
    }
    int incl = s;
    #pragma unroll
    for (int off = 1; off < 64; off <<= 1) {
        int n = __shfl_up(incl, off);
        if (lane >= off) incl += n;
    }
    if (lane == 63) wsum2[wid] = incl;
    __syncthreads();
    int wbase = 0;
    #pragma unroll
    for (int k = 0; k < 4; ++k) if (k < wid) wbase += wsum2[k];
    if (tid < NB) bucketbase[tid] = wbase + incl - s;
    if (tid == 0) bucketbase[NB] = E;
}

// pass A2: per-bucket column scan of blockhist -> per-block write cursors
__global__ __launch_bounds__(64) void offsets_kernel(const int* __restrict__ bucketbase,
        int* __restrict__ blockhist, int NB) {
    int b = blockIdx.x;
    int lane = threadIdx.x;
    int v[PER_LANE];
    int base = lane * PER_LANE;
    int s = 0;
    #pragma unroll
    for (int k = 0; k < PER_LANE; ++k) {
        int i = base + k;
        v[k] = (i < NBLK_SCAT) ? blockhist[i * 256 + b] : 0;
        s += v[k];
    }
    int incl = s;
    #pragma unroll
    for (int off = 1; off < 64; off <<= 1) {
        int n = __shfl_up(incl, off);
        if (lane >= off) incl += n;
    }
    int excl = incl - s + bucketbase[b];
    #pragma unroll
    for (int k = 0; k < PER_LANE; ++k) {
        int i = base + k;
        if (i < NBLK_SCAT) { blockhist[i * 256 + b] = excl; excl += v[k]; }
    }
}

// pass A3: scatter edges to bucket regions using LDS cursors
__global__ __launch_bounds__(256) void scatterA_kernel(const int* __restrict__ src,
        const int* __restrict__ dst, const int* __restrict__ blockhist,
        int* __restrict__ buf, int E, int chunk) {
    __shared__ int lcur[256];
    int tid = threadIdx.x, blk = blockIdx.x;
    lcur[tid] = blockhist[blk * 256 + tid];
    __syncthreads();
    int s = blk * chunk, e = s + chunk; if (e > E) e = E;
    for (int i = s + tid; i < e; i += 256) {
        int d = dst[i];
        int b = d >> 8;
        int p = atomicAdd(&lcur[b], 1);
        buf[p] = ((d & 255) << 24) | src[i];    // pack local-dst | src (src < 2^24)
    }
}

// pass B: per bucket: local degree hist + scan (writes rowstart, dis), permute to csr
__global__ __launch_bounds__(256) void bucket_to_csr_kernel(const int* __restrict__ buf,
        const int* __restrict__ bucketbase, int* __restrict__ rowstart,
        float* __restrict__ dis, int* __restrict__ csr, int N, int E) {
    __shared__ int ldeg[256];
    __shared__ int cur[256];
    __shared__ int wsum2[4];
    __shared__ int stage[STAGE_CAP];
    int b = blockIdx.x;
    int nodeStart = b << 8;
    int nodeEnd = nodeStart + 256; if (nodeEnd > N) nodeEnd = N;
    int nloc = nodeEnd - nodeStart;
    int base = bucketbase[b];
    int nE = bucketbase[b + 1] - base;
    int tid = threadIdx.x;
    int lane = tid & 63, wid = tid >> 6;
    ldeg[tid] = 0;
    __syncthreads();
    for (int i = tid; i < nE; i += 256)
        atomicAdd(&ldeg[((unsigned)buf[base + i]) >> 24], 1);
    __syncthreads();
    int d = ldeg[tid];
    int incl = d;
    #pragma unroll
    for (int off = 1; off < 64; off <<= 1) {
        int n = __shfl_up(incl, off);
        if (lane >= off) incl += n;
    }
    if (lane == 63) wsum2[wid] = incl;
    __syncthreads();
    int wbase = 0;
    #pragma unroll
    for (int k = 0; k < 4; ++k) if (k < wid) wbase += wsum2[k];
    int excl = wbase + incl - d;
    cur[tid] = excl;
    if (tid < nloc) {
        rowstart[nodeStart + tid] = base + excl;
        dis[nodeStart + tid] = rsqrtf((float)d + 1.0f);
    }
    if (b == 0 && tid == 0) rowstart[N] = E;
    __syncthreads();
    if (nE <= STAGE_CAP) {
        for (int i = tid; i < nE; i += 256) {
            int u = buf[base + i];
            int l = ((unsigned)u) >> 24;
            int p = atomicAdd(&cur[l], 1);
            stage[p] = u & 0xFFFFFF;
        }
        __syncthreads();
        for (int i = tid; i < nE; i += 256) csr[base + i] = stage[i];
    } else {
        for (int i = tid; i < nE; i += 256) {
            int u = buf[base + i];
            int l = ((unsigned)u) >> 24;
            int p = atomicAdd(&cur[l], 1);
            csr[base + p] = u & 0xFFFFFF;
        }
    }
}

// ---------------------------------------------------------------- layer 1 GEMM (IN=3) -> bf16 mt
// one thread = 2 channels (uint store)
__global__ void mt1_kernel(const float* __restrict__ x, const float* __restrict__ W1,
                           const float* __restrict__ dis, unsigned int* __restrict__ mt2, int N) {
    int t = blockIdx.x * blockDim.x + threadIdx.x;
    if (t < N * 32) {
        int v = t >> 5, c2 = t & 31;
        float x0 = x[v * 3 + 0], x1 = x[v * 3 + 1], x2 = x[v * 3 + 2];
        float dv = dis[v];
        float ma = (x0 * W1[0 * HH + 2 * c2] + x1 * W1[1 * HH + 2 * c2] + x2 * W1[2 * HH + 2 * c2]) * dv;
        float mb = (x0 * W1[0 * HH + 2 * c2 + 1] + x1 * W1[1 * HH + 2 * c2 + 1] + x2 * W1[2 * HH + 2 * c2 + 1]) * dv;
        mt2[t] = (unsigned)f2bf(ma) | ((unsigned)f2bf(mb) << 16);
    }
}

// ---------------------------------------------------------------- 64x64 GEMM + row scale -> bf16 mt
// One 64-node tile per block. W^T and h tile staged in LDS as packed bf16x2
// (pad 34 -> 2-way bank alias only). Scalar accumulator per thread.
__global__ __launch_bounds__(256) void gemm_scale_kernel(const float* __restrict__ h,
        const float* __restrict__ W, const float* __restrict__ dis,
        unsigned short* __restrict__ mt, int N) {
    __shared__ unsigned int wsp[HH * 34];
    __shared__ unsigned int hs2[64 * 34];
    int tid = threadIdx.x;
    int lane = tid & 63, wid = tid >> 6;
    {
        int c = tid & 63;
        for (int k2 = tid >> 6; k2 < 32; k2 += 4) {
            float a = W[(2 * k2) * HH + c];
            float b = W[(2 * k2 + 1) * HH + c];
            wsp[c * 34 + k2] = (unsigned)f2bf(a) | ((unsigned)f2bf(b) << 16);
        }
    }
    int v0 = blockIdx.x * 64;
    int nv = N - v0; if (nv > 64) nv = 64;
    for (int idx = tid; idx < 64 * 32; idx += 256) {
        int n = idx >> 5, k2 = idx & 31;
        int vsrc = v0 + ((n < nv) ? n : 0);
        float a = h[(size_t)vsrc * HH + 2 * k2];
        float b = h[(size_t)vsrc * HH + 2 * k2 + 1];
        hs2[n * 34 + k2] = (unsigned)f2bf(a) | ((unsigned)f2bf(b) << 16);
    }
    __syncthreads();
    for (int n = wid * 16; n < wid * 16 + 16; ++n) {
        int vg = v0 + n;
        if (n >= nv) break;
        float acc = 0.f;
        #pragma unroll 4
        for (int k2g = 0; k2g < 16; ++k2g) {
            uint2 wv = *(const uint2*)&wsp[lane * 34 + 2 * k2g];
            uint2 hv = *(const uint2*)&hs2[n * 34 + 2 * k2g];
            acc = fmaf(bflo(hv.x), bflo(wv.x), acc);
            acc = fmaf(bfhi(hv.x), bfhi(wv.x), acc);
            acc = fmaf(bflo(hv.y), bflo(wv.y), acc);
            acc = fmaf(bfhi(hv.y), bfhi(wv.y), acc);
        }
        mt[(size_t)vg * HH + lane] = f2bf(acc * dis[vg]);
    }
}

// ---------------------------------------------------------------- gather + bias + BN + ReLU
// Dual-row gather: lanes 0-31 gather row idx[j], lanes 32-63 row idx[j+1];
// each lane reads a uint (2 channels). Halves combined via shfl_xor(32).
__global__ __launch_bounds__(256) void gather_bn_kernel(const unsigned short* __restrict__ mt,
        const int* __restrict__ rowstart, const int* __restrict__ csr_src,
        const float* __restrict__ dis, const float* __restrict__ bias,
        const float* __restrict__ gam, const float* __restrict__ beta,
        const float* __restrict__ mu, const float* __restrict__ var,
        float* __restrict__ hout, int N) {
    int lane = threadIdx.x & 63, wid = threadIdx.x >> 6;
    int v = blockIdx.x * 4 + wid;
    if (v >= N) return;
    int half = lane >> 5;          // 0 or 1
    int hl = lane & 31;            // channel-pair index
    int start = rowstart[v], end = rowstart[v + 1];
    float ax = 0.f, ay = 0.f;
    if (half == 0) {               // self-loop term
        unsigned u = *(const unsigned*)&mt[(size_t)v * HH + 2 * hl];
        ax = bflo(u); ay = bfhi(u);
    }
    for (int base = start; base < end; base += 64) {
        int idx = (base + lane < end) ? csr_src[base + lane] : 0;
        int cnt = end - base; if (cnt > 64) cnt = 64;
        int j = 0;
        for (; j + 15 < cnt; j += 16) {   // 8 dual-row loads
            int p0 = __shfl(idx, j + 0 + half);
            int p1 = __shfl(idx, j + 2 + half);
            int p2 = __shfl(idx, j + 4 + half);
            int p3 = __shfl(idx, j + 6 + half);
            int p4 = __shfl(idx, j + 8 + half);
            int p5 = __shfl(idx, j + 10 + half);
            int p6 = __shfl(idx, j + 12 + half);
            int p7 = __shfl(idx, j + 14 + half);
            unsigned u0 = *(const unsigned*)&mt[(size_t)p0 * HH + 2 * hl];
            unsigned u1 = *(const unsigned*)&mt[(size_t)p1 * HH + 2 * hl];
            unsigned u2 = *(const unsigned*)&mt[(size_t)p2 * HH + 2 * hl];
            unsigned u3 = *(const unsigned*)&mt[(size_t)p3 * HH + 2 * hl];
            unsigned u4 = *(const unsigned*)&mt[(size_t)p4 * HH + 2 * hl];
            unsigned u5 = *(const unsigned*)&mt[(size_t)p5 * HH + 2 * hl];
            unsigned u6 = *(const unsigned*)&mt[(size_t)p6 * HH + 2 * hl];
            unsigned u7 = *(const unsigned*)&mt[(size_t)p7 * HH + 2 * hl];
            ax += bflo(u0); ay += bfhi(u0);
            ax += bflo(u1); ay += bfhi(u1);
            ax += bflo(u2); ay += bfhi(u2);
            ax += bflo(u3); ay += bfhi(u3);
            ax += bflo(u4); ay += bfhi(u4);
            ax += bflo(u5); ay += bfhi(u5);
            ax += bflo(u6); ay += bfhi(u6);
            ax += bflo(u7); ay += bfhi(u7);
        }
        for (; j + 1 < cnt; j += 2) {     // dual tail
            int p = __shfl(idx, j + half);
            unsigned u = *(const unsigned*)&mt[(size_t)p * HH + 2 * hl];
            ax += bflo(u); ay += bfhi(u);
        }
        if (j < cnt) {                    // odd edge: half 0 only
            int p = __shfl(idx, j);
            if (half == 0) {
                unsigned u = *(const unsigned*)&mt[(size_t)p * HH + 2 * hl];
                ax += bflo(u); ay += bfhi(u);
            }
        }
    }
    // combine halves
    float ox = __shfl_xor(ax, 32);
    float oy = __shfl_xor(ay, 32);
    if (half == 0) {
        ax += ox; ay += oy;
        float dv = dis[v];
        float2 bi = *(const float2*)&bias[2 * hl];
        float2 gm = *(const float2*)&gam[2 * hl];
        float2 be = *(const float2*)&beta[2 * hl];
        float2 mm = *(const float2*)&mu[2 * hl];
        float2 vv = *(const float2*)&var[2 * hl];
        float vx = (ax * dv + bi.x - mm.x) * rsqrtf(vv.x + EPS) * gm.x + be.x;
        float vy = (ay * dv + bi.y - mm.y) * rsqrtf(vv.y + EPS) * gm.y + be.y;
        float2 o = make_float2(fmaxf(vx, 0.f), fmaxf(vy, 0.f));
        *(float2*)&hout[(size_t)v * HH + 2 * hl] = o;
    }
}

// ---------------------------------------------------------------- pool partial sums
__global__ __launch_bounds__(256) void pool_partial_kernel(const float* __restrict__ h,
        const int* __restrict__ batch, float* __restrict__ gsum, int N, int chunk) {
    int lane = threadIdx.x & 63, wid = threadIdx.x >> 6;
    int w = blockIdx.x * 4 + wid;
    int start = w * chunk;
    int end = start + chunk; if (end > N) end = N;
    if (start >= end) return;
    int g = batch[start];
    float acc = 0.f;
    for (int i = start; i < end; ++i) {
        int gi = batch[i];
        if (gi != g) {
            atomicAdd(&gsum[g * HH + lane], acc);
            acc = 0.f; g = gi;
        }
        acc += h[i * HH + lane];
    }
    atomicAdd(&gsum[g * HH + lane], acc);
}

// ---------------------------------------------------------------- MLP heads (+ mean divide)
__global__ __launch_bounds__(64) void heads_kernel(const float* __restrict__ gsum,
        const int* __restrict__ batch, int N,
        const float* __restrict__ thW1, const float* __restrict__ thb1,
        const float* __restrict__ thW2, const float* __restrict__ thb2,
        const float* __restrict__ lhW1, const float* __restrict__ lhb1,
        const float* __restrict__ lhW2, const float* __restrict__ lhb2,
        const float* __restrict__ shW1, const float* __restrict__ shb1,
        const float* __restrict__ shW2, const float* __restrict__ shb2,
        float* __restrict__ out, int B) {
    int g = blockIdx.x, t = threadIdx.x;
    __shared__ float ge[HH];
    __shared__ float hT[32], hL[32], hS[16];
    int lo = lower_bound_i(batch, N, g);
    int hi = lower_bound_i(batch, N, g + 1);
    float cnt = (float)(hi - lo);
    ge[t] = gsum[g * HH + t] / fmaxf(cnt, 1.0f);
    __syncthreads();
    if (t < 32) {
        float a = thb1[t];
        for (int k = 0; k < HH; ++k) a += ge[k] * thW1[k * 32 + t];
        hT[t] = fmaxf(a, 0.f);
    } else {
        int j = t - 32;
        float a = lhb1[j];
        for (int k = 0; k < HH; ++k) a += ge[k] * lhW1[k * 32 + j];
        hL[j] = fmaxf(a, 0.f);
    }
    __syncthreads();
    if (t < 16) {
        float a = shb1[t];
        for (int k = 0; k < HH; ++k) a += ge[k] * shW1[k * 16 + t];
        hS[t] = fmaxf(a, 0.f);
    }
    __syncthreads();
    if (t < 6) {
        float a = thb2[t];
        for (int j = 0; j < 32; ++j) a += hT[j] * thW2[j * 6 + t];
        out[g * 6 + t] = a;
    } else if (t >= 8 && t < 10) {
        int o = t - 8;
        float a = lhb2[o];
        for (int j = 0; j < 32; ++j) a += hL[j] * lhW2[j * 2 + o];
        out[B * 6 + g * 2 + o] = 1.f / (1.f + expf(-a));
    } else if (t == 12) {
        float a = shb2[0];
        for (int j = 0; j < 16; ++j) a += hS[j] * shW2[j];
        out[B * 8 + g] = 1.f / (1.f + expf(-a));
    }
}

// ---------------------------------------------------------------- launch
extern "C" void kernel_launch(void* const* d_in, const int* in_sizes, int n_in,
                              void* d_out, int out_size, void* d_ws, size_t ws_size,
                              hipStream_t stream) {
    const float* x   = (const float*)d_in[0];
    const int*   ei  = (const int*)d_in[1];
    const int*   bat = (const int*)d_in[2];
    const float* W1 = (const float*)d_in[3];  const float* b1 = (const float*)d_in[4];
    const float* W2 = (const float*)d_in[5];  const float* b2 = (const float*)d_in[6];
    const float* W3 = (const float*)d_in[7];  const float* b3 = (const float*)d_in[8];
    const float* bn1g = (const float*)d_in[9];  const float* bn1b = (const float*)d_in[10];
    const float* bn1m = (const float*)d_in[11]; const float* bn1v = (const float*)d_in[12];
    const float* bn2g = (const float*)d_in[13]; const float* bn2b = (const float*)d_in[14];
    const float* bn2m = (const float*)d_in[15]; const float* bn2v = (const float*)d_in[16];
    const float* bn3g = (const float*)d_in[17]; const float* bn3b = (const float*)d_in[18];
    const float* bn3m = (const float*)d_in[19]; const float* bn3v = (const float*)d_in[20];
    const float* thW1 = (const float*)d_in[21]; const float* thb1 = (const float*)d_in[22];
    const float* thW2 = (const float*)d_in[23]; const float* thb2 = (const float*)d_in[24];
    const float* lhW1 = (const float*)d_in[25]; const float* lhb1 = (const float*)d_in[26];
    const float* lhW2 = (const float*)d_in[27]; const float* lhb2 = (const float*)d_in[28];
    const float* shW1 = (const float*)d_in[29]; const float* shb1 = (const float*)d_in[30];
    const float* shW2 = (const float*)d_in[31]; const float* shb2 = (const float*)d_in[32];
    float* out = (float*)d_out;

    const int N = in_sizes[0] / 3;
    const int E = in_sizes[1] / 2;
    const int B = out_size / 9;          // 6 + 2 + 1 per graph
    const int NB = (N + 255) >> 8;       // buckets of 256 nodes
    const int* esrc = ei;
    const int* edst = ei + E;

    // workspace layout (256B aligned)
    char* w = (char*)d_ws;
    size_t off = 0;
    auto alloc = [&](size_t bytes) -> void* {
        void* p = w + off;
        off += (bytes + 255) & ~(size_t)255;
        return p;
    };
    int*   rowstart   = (int*)  alloc((size_t)(N + 1) * 4);
    float* dis        = (float*)alloc((size_t)N * 4);
    int*   csr        = (int*)  alloc((size_t)E * 4);
    int*   blockhist  = (int*)  alloc((size_t)NBLK_SCAT * 256 * 4);
    int*   bucketbase = (int*)  alloc((size_t)(NB + 1) * 4);
    float* hbuf       = (float*)alloc((size_t)N * HH * 4);
    unsigned short* mtbuf = (unsigned short*)alloc((size_t)N * HH * 2);
    float* gsum       = (float*)alloc((size_t)B * HH * 4);
    int*   bucketbuf  = (int*)mtbuf;     // reuse: free until mt1_kernel (E*4 <= N*HH*2)
    (void)ws_size;

    const int TB = 256;
    const int echunk = (E + NBLK_SCAT - 1) / NBLK_SCAT;
    // CSR build: hist -> bucketscan -> offsets -> scatter -> per-bucket deg/scan/permute
    init_kernel<<<(B * HH + TB - 1) / TB, TB, 0, stream>>>(gsum, B * HH);
    hist_kernel<<<NBLK_SCAT, TB, 0, stream>>>(edst, blockhist, E, echunk);
    bucketscan_kernel<<<1, TB, 0, stream>>>(blockhist, bucketbase, NB, E);
    offsets_kernel<<<NB, 64, 0, stream>>>(bucketbase, blockhist, NB);
    scatterA_kernel<<<NBLK_SCAT, TB, 0, stream>>>(esrc, edst, blockhist, bucketbuf, E, echunk);
    bucket_to_csr_kernel<<<NB, TB, 0, stream>>>(bucketbuf, bucketbase, rowstart, dis, csr, N, E);

    int gatherBlocks = (N + 3) / 4;
    int gemmBlocks = (N + 63) / 64;
    // layer 1
    mt1_kernel<<<(N * 32 + TB - 1) / TB, TB, 0, stream>>>(x, W1, dis, (unsigned int*)mtbuf, N);
    gather_bn_kernel<<<gatherBlocks, TB, 0, stream>>>(mtbuf, rowstart, csr, dis,
            b1, bn1g, bn1b, bn1m, bn1v, hbuf, N);
    // layer 2
    gemm_scale_kernel<<<gemmBlocks, TB, 0, stream>>>(hbuf, W2, dis, mtbuf, N);
    gather_bn_kernel<<<gatherBlocks, TB, 0, stream>>>(mtbuf, rowstart, csr, dis,
            b2, bn2g, bn2b, bn2m, bn2v, hbuf, N);
    // layer 3
    gemm_scale_kernel<<<gemmBlocks, TB, 0, stream>>>(hbuf, W3, dis, mtbuf, N);
    gather_bn_kernel<<<gatherBlocks, TB, 0, stream>>>(mtbuf, rowstart, csr, dis,
            b3, bn3g, bn3b, bn3m, bn3v, hbuf, N);

    // pool (gsum zeroed in init_kernel) + heads
    const int PW_BLOCKS = 512;
    int chunk = (N + PW_BLOCKS * 4 - 1) / (PW_BLOCKS * 4);
    pool_partial_kernel<<<PW_BLOCKS, TB, 0, stream>>>(hbuf, bat, gsum, N, chunk);

    heads_kernel<<<B, 64, 0, stream>>>(gsum, bat, N, thW1, thb1, thW2, thb2,
            lhW1, lhb1, lhW2, lhb2, shW1, shb1, shW2, shb2, out, B);
}